// Round 3
// baseline (442.469 us; speedup 1.0000x reference)
//
#include <hip/hip_runtime.h>
#include <hip/hip_bf16.h>

#define BATCH 131072
#define DH 128
#define D3 384

typedef float   f32x4  __attribute__((ext_vector_type(4)));
typedef __bf16  bf16x8 __attribute__((ext_vector_type(8)));
typedef unsigned short u16x8 __attribute__((ext_vector_type(8)));

__device__ __forceinline__ unsigned short f2bf(float f) {
    // round-to-nearest-even f32 -> bf16 (inputs are finite)
    unsigned u = __builtin_bit_cast(unsigned, f);
    u += 0x7fffu + ((u >> 16) & 1u);
    return (unsigned short)(u >> 16);
}
__device__ __forceinline__ float fast_tanh(float v) {
    float e = __expf(2.0f * v);
    return (e - 1.0f) * __builtin_amdgcn_rcpf(e + 1.0f);
}
__device__ __forceinline__ float fast_sigmoid(float z) {
    return __builtin_amdgcn_rcpf(1.0f + __expf(-z));
}

// W (f32, [128][384] row-major) -> wt (bf16 bits, [384][128] row-major).
// Coalesced reads (one W row per block), strided writes (tiny, L2-resident).
__global__ void prep_kernel(const float* __restrict__ W, unsigned short* __restrict__ wt) {
    const int k = blockIdx.x;    // 0..127
    const int e = threadIdx.x;   // 0..383
    wt[e * DH + k] = f2bf(W[k * D3 + e]);
}

// One wave = 16 batch rows x 64 d-columns (half a tile).
// MFMA with A = Wt tile, B = h tile  =>  lane (c,g) holds batch row R+c and
// e = EBASE + 4g + reg  (4 consecutive e per fragment) -> float4 epilogue.
// Accumulator is initialized with x, so acc_out = x + h@W directly.
__global__ __launch_bounds__(256) void fused_kernel(
    const float* __restrict__ h, const float* __restrict__ x,
    const unsigned short* __restrict__ wt, float* __restrict__ out)
{
    const int wave = (blockIdx.x * 256 + (int)threadIdx.x) >> 6;  // 0..16383
    const int lane = threadIdx.x & 63;
    const int c    = lane & 15;     // batch row within tile (D col)
    const int g    = lane >> 4;     // k-slot group / D row group
    const int tile = wave >> 1;     // 0..8191
    const int q    = wave & 1;      // d-half: 0 -> d[0,64), 1 -> d[64,128)
    const int row  = tile * 16 + c;
    const int dbase = 64 * q + 4 * g;            // + 16*n + reg gives d

    const float* xr = x + (size_t)row * D3;
    const float* hr = h + (size_t)row * DH;

    // ---- acc init = x (issues all x loads up front; they overlap the MFMA chain)
    f32x4 acc[3][4];
    #pragma unroll
    for (int grp = 0; grp < 3; ++grp) {
        #pragma unroll
        for (int n = 0; n < 4; ++n) {
            const f32x4* p = reinterpret_cast<const f32x4*>(xr + grp * DH + dbase + 16 * n);
            acc[grp][n] = __builtin_nontemporal_load(p);   // x is read-once: bypass cache
        }
    }

    // ---- B operand: this tile's h rows, K=128 in 4 steps of 32
    // slot mapping: lane group g, reg j -> k = 32*s + 8*g + j
    bf16x8 b[4];
    #pragma unroll
    for (int s = 0; s < 4; ++s) {
        const float4* p = reinterpret_cast<const float4*>(hr + 32 * s + 8 * g);
        float4 u0 = p[0], u1 = p[1];
        u16x8 t;
        t[0]=f2bf(u0.x); t[1]=f2bf(u0.y); t[2]=f2bf(u0.z); t[3]=f2bf(u0.w);
        t[4]=f2bf(u1.x); t[5]=f2bf(u1.y); t[6]=f2bf(u1.z); t[7]=f2bf(u1.w);
        b[s] = __builtin_bit_cast(bf16x8, t);
    }

    // ---- MFMA: A frags streamed from L2-resident Wt
    // frag (grp,n) covers e in [EBASE, EBASE+16), EBASE = grp*128 + 64q + 16n
    #pragma unroll
    for (int grp = 0; grp < 3; ++grp) {
        #pragma unroll
        for (int n = 0; n < 4; ++n) {
            const int ebase = grp * DH + 64 * q + 16 * n;
            const u16x8* wp = reinterpret_cast<const u16x8*>(wt + (size_t)(ebase + c) * DH);
            #pragma unroll
            for (int s = 0; s < 4; ++s) {
                acc[grp][n] = __builtin_amdgcn_mfma_f32_16x16x32_bf16(
                    __builtin_bit_cast(bf16x8, wp[4 * s + g]), b[s], acc[grp][n], 0, 0, 0);
            }
        }
    }

    // ---- epilogue: fully float4 (acc already holds x + recurrent)
    float* o0 = out + (size_t)row * DH;
    float* o1 = out + (size_t)BATCH * DH + (size_t)row * DH;
    #pragma unroll
    for (int n = 0; n < 4; ++n) {
        const int d = dbase + 16 * n;
        f32x4 hv = *reinterpret_cast<const f32x4*>(hr + d);
        f32x4 v0, v1;
        #pragma unroll
        for (int j = 0; j < 4; ++j) {
            float it = fast_tanh(acc[0][n][j]);
            float ig = fast_sigmoid(acc[1][n][j]);
            float og = fast_sigmoid(acc[2][n][j]);
            float hn = it * ig + hv[j] * (1.0f - ig);
            v0[j] = hn;
            v1[j] = fast_tanh(hn) * og;
        }
        __builtin_nontemporal_store(v0, reinterpret_cast<f32x4*>(o0 + d));
        __builtin_nontemporal_store(v1, reinterpret_cast<f32x4*>(o1 + d));
    }
}

extern "C" void kernel_launch(void* const* d_in, const int* in_sizes, int n_in,
                              void* d_out, int out_size, void* d_ws, size_t ws_size,
                              hipStream_t stream) {
    const float* h = (const float*)d_in[0];
    const float* x = (const float*)d_in[1];
    const float* W = (const float*)d_in[2];
    float* out = (float*)d_out;
    unsigned short* wt = (unsigned short*)d_ws;   // 384*128 bf16 = 96 KiB

    prep_kernel<<<DH, D3, 0, stream>>>(W, wt);                    // 128 blocks x 384
    fused_kernel<<<BATCH / 16 * 2 / 4, 256, 0, stream>>>(h, x, wt, out); // 4096 wg
}

// Round 4
// 365.405 us; speedup vs baseline: 1.2109x; 1.2109x over previous
//
#include <hip/hip_runtime.h>
#include <hip/hip_bf16.h>

#define BATCH 131072
#define DH 128
#define D3 384

typedef float   f32x4  __attribute__((ext_vector_type(4)));
typedef __bf16  bf16x8 __attribute__((ext_vector_type(8)));
typedef unsigned short u16x8 __attribute__((ext_vector_type(8)));

__device__ __forceinline__ unsigned short f2bf(float f) {
    // round-to-nearest-even f32 -> bf16 (inputs are finite)
    unsigned u = __builtin_bit_cast(unsigned, f);
    u += 0x7fffu + ((u >> 16) & 1u);
    return (unsigned short)(u >> 16);
}
__device__ __forceinline__ float fast_tanh(float v) {
    float e = __expf(2.0f * v);
    return (e - 1.0f) * __builtin_amdgcn_rcpf(e + 1.0f);
}
__device__ __forceinline__ float fast_sigmoid(float z) {
    return __builtin_amdgcn_rcpf(1.0f + __expf(-z));
}

// W (f32, [128][384] row-major) -> wt (bf16 bits, [384][128] row-major).
__global__ void prep_kernel(const float* __restrict__ W, unsigned short* __restrict__ wt) {
    const int k = blockIdx.x;    // 0..127
    const int e = threadIdx.x;   // 0..383
    wt[e * DH + k] = f2bf(W[k * D3 + e]);
}

// wg = 64 batch rows x one d-half (q). 4 waves, each 16 rows x 64 d-cols.
// Wt slice for this wg (192 rows x 256B = 48KB) is staged once into LDS
// (XOR-swizzled), shared by all 4 waves. acc is initialized with x so
// acc_out = x + h@W; epilogue is pure math + float4 h-load + float4 stores.
__global__ __launch_bounds__(256, 3) void fused_kernel(
    const float* __restrict__ h, const float* __restrict__ x,
    const unsigned short* __restrict__ wt, float* __restrict__ out)
{
    __shared__ unsigned char wlds[192 * 256];   // 48 KB

    const int tid  = threadIdx.x;
    const int w    = tid >> 6;      // wave 0..3
    const int lane = tid & 63;
    const int c    = lane & 15;     // batch row within wave tile
    const int g    = lane >> 4;     // k-slot group / d sub-group
    const int q    = blockIdx.x & 1;              // d-half
    const int RB   = (blockIdx.x >> 1) * 64;      // wg batch-row base
    const int row  = RB + 16 * w + c;
    const int dbase = 64 * q + 4 * g;

    // ---- 1. staging loads: Wt rows e = grp*128 + 64q + m  (192 rows x 256B)
    // chunk i = tid + 256*it ; lds row l = i>>4 ; 16B slot = i&15. Coalesced.
    u16x8 sv[12];
    #pragma unroll
    for (int it = 0; it < 12; ++it) {
        const int i = tid + 256 * it;
        const int l = i >> 4;                    // 0..191
        const int e = (l >> 6) * 128 + 64 * q + (l & 63);
        sv[it] = *reinterpret_cast<const u16x8*>(wt + e * DH + (i & 15) * 8);
    }

    // ---- 2. x loads -> acc init (12 independent f32x4, issued early)
    const float* xr = x + (size_t)row * D3;
    f32x4 acc[3][4];
    #pragma unroll
    for (int grp = 0; grp < 3; ++grp)
        #pragma unroll
        for (int n = 0; n < 4; ++n)
            acc[grp][n] = *reinterpret_cast<const f32x4*>(xr + grp * DH + dbase + 16 * n);

    // ---- 3. h loads (B-operand raw data, 8 independent float4)
    const float* hr = h + (size_t)row * DH;
    f32x4 ht[8];
    #pragma unroll
    for (int s = 0; s < 4; ++s) {
        const f32x4* p = reinterpret_cast<const f32x4*>(hr + 32 * s + 8 * g);
        ht[2 * s]     = p[0];
        ht[2 * s + 1] = p[1];
    }

    // ---- 4. swizzled ds_write of the staged Wt slice
    #pragma unroll
    for (int it = 0; it < 12; ++it) {
        const int i  = tid + 256 * it;
        const int l  = i >> 4;
        const int bo = ((i & 15) * 16) ^ ((l & 7) << 4);
        *reinterpret_cast<u16x8*>(&wlds[l * 256 + bo]) = sv[it];
    }

    // ---- 5. pack B frags (k = 32*s + 8*g + j)
    bf16x8 bfr[4];
    #pragma unroll
    for (int s = 0; s < 4; ++s) {
        u16x8 t;
        #pragma unroll
        for (int j = 0; j < 4; ++j) { t[j] = f2bf(ht[2*s][j]); t[4+j] = f2bf(ht[2*s+1][j]); }
        bfr[s] = __builtin_bit_cast(bf16x8, t);
    }

    __syncthreads();

    // ---- 6. MFMA: A frags from swizzled LDS
    // frag (grp,n): lds row l = grp*64 + 16n + c, bytes (64s+16g) ^ ((c&7)<<4)
    #pragma unroll
    for (int grp = 0; grp < 3; ++grp) {
        #pragma unroll
        for (int n = 0; n < 4; ++n) {
            const unsigned char* base = &wlds[(grp * 64 + 16 * n + c) * 256];
            const int sw = (c & 7) << 4;
            #pragma unroll
            for (int s = 0; s < 4; ++s) {
                u16x8 av = *reinterpret_cast<const u16x8*>(base + ((64 * s + 16 * g) ^ sw));
                acc[grp][n] = __builtin_amdgcn_mfma_f32_16x16x32_bf16(
                    __builtin_bit_cast(bf16x8, av), bfr[s], acc[grp][n], 0, 0, 0);
            }
        }
    }

    // ---- 7. epilogue: fully float4, normal (cached) stores
    float* o0 = out + (size_t)row * DH;
    float* o1 = out + (size_t)BATCH * DH + (size_t)row * DH;
    #pragma unroll
    for (int n = 0; n < 4; ++n) {
        const int d = dbase + 16 * n;
        f32x4 hv = *reinterpret_cast<const f32x4*>(hr + d);
        f32x4 v0, v1;
        #pragma unroll
        for (int j = 0; j < 4; ++j) {
            float it = fast_tanh(acc[0][n][j]);
            float ig = fast_sigmoid(acc[1][n][j]);
            float og = fast_sigmoid(acc[2][n][j]);
            float hn = it * ig + hv[j] * (1.0f - ig);
            v0[j] = hn;
            v1[j] = fast_tanh(hn) * og;
        }
        *reinterpret_cast<f32x4*>(o0 + d) = v0;
        *reinterpret_cast<f32x4*>(o1 + d) = v1;
    }
}

extern "C" void kernel_launch(void* const* d_in, const int* in_sizes, int n_in,
                              void* d_out, int out_size, void* d_ws, size_t ws_size,
                              hipStream_t stream) {
    const float* h = (const float*)d_in[0];
    const float* x = (const float*)d_in[1];
    const float* W = (const float*)d_in[2];
    float* out = (float*)d_out;
    unsigned short* wt = (unsigned short*)d_ws;   // 384*128 bf16 = 96 KiB

    prep_kernel<<<DH, D3, 0, stream>>>(W, wt);                 // 128 x 384
    fused_kernel<<<(BATCH / 64) * 2, 256, 0, stream>>>(h, x, wt, out);  // 4096 wg
}